// Round 1
// baseline (298.069 us; speedup 1.0000x reference)
//
#include <hip/hip_runtime.h>

#define NC 91
#define NB 32
#define HW (1024 * 1024)

#define THREADS 256
#define PPT 128                         // pixels per thread
#define PIX_PER_BLOCK (THREADS * PPT)   // 32768
#define NW 46                           // ceil(91/2) packed words actually used
#define WPT 47                          // padded to odd stride -> full bank spread

// Per-thread private histogram, 2 bins packed per 32-bit word (16-bit fields).
// Max increments per thread per bin = 2*PPT = 256 << 65536, so no field carry.
// atomicAdd on a private address compiles to fire-and-forget ds_add_u32:
// 1 DS instruction per increment, zero same-address contention.

__global__ __launch_bounds__(256) void hist_kernel(const int* __restrict__ x,
                                                   const int* __restrict__ t,
                                                   int* __restrict__ g_hist,
                                                   int* __restrict__ g_inter) {
    __shared__ int s_hist[THREADS * WPT];   // 48,128 B packed private histograms
    __shared__ int s_inter[NC];             // block-wide intersection (rare hits)
    __shared__ int s_plo[4][NW];
    __shared__ int s_phi[4][NW];

    const int tid = threadIdx.x;
    int* hp = &s_hist[tid * WPT];
#pragma unroll
    for (int j = 0; j < WPT; ++j) hp[j] = 0;
    if (tid < NC) s_inter[tid] = 0;
    __syncthreads();

    const int b = blockIdx.y;
    const long base = (long)b * HW + (long)blockIdx.x * PIX_PER_BLOCK;
    const int4* __restrict__ x4 = (const int4*)(x + base);
    const int4* __restrict__ t4 = (const int4*)(t + base);

#pragma unroll 4
    for (int i = 0; i < PPT / 4; ++i) {
        int4 xv = x4[i * THREADS + tid];
        int4 tv = t4[i * THREADS + tid];

        atomicAdd(&hp[xv.x >> 1], 1 << ((xv.x & 1) << 4));
        atomicAdd(&hp[tv.x >> 1], 1 << ((tv.x & 1) << 4));
        if (xv.x == tv.x) atomicAdd(&s_inter[xv.x], 1);

        atomicAdd(&hp[xv.y >> 1], 1 << ((xv.y & 1) << 4));
        atomicAdd(&hp[tv.y >> 1], 1 << ((tv.y & 1) << 4));
        if (xv.y == tv.y) atomicAdd(&s_inter[xv.y], 1);

        atomicAdd(&hp[xv.z >> 1], 1 << ((xv.z & 1) << 4));
        atomicAdd(&hp[tv.z >> 1], 1 << ((tv.z & 1) << 4));
        if (xv.z == tv.z) atomicAdd(&s_inter[xv.z], 1);

        atomicAdd(&hp[xv.w >> 1], 1 << ((xv.w & 1) << 4));
        atomicAdd(&hp[tv.w >> 1], 1 << ((tv.w & 1) << 4));
        if (xv.w == tv.w) atomicAdd(&s_inter[xv.w], 1);
    }
    __syncthreads();

    // Stage 1: reduce 256 private copies in 4 chunks of 64, unpacking 16-bit
    // fields into 32-bit partials (max 64*256 = 16384 per field, no overflow).
    const int chunk = tid >> 6;
    const int w = tid & 63;
    if (w < NW) {
        int lo = 0, hi = 0;
        const int kb = chunk * 64;
        for (int k = 0; k < 64; ++k) {
            unsigned v = (unsigned)s_hist[(kb + k) * WPT + w];
            lo += (int)(v & 0xffffu);
            hi += (int)(v >> 16);
        }
        s_plo[chunk][w] = lo;
        s_phi[chunk][w] = hi;
    }
    __syncthreads();

    // Stage 2: combine 4 chunk partials, one global atomic per class.
    if (tid < NC) {
        const int w2 = tid >> 1;
        int sum;
        if (tid & 1) sum = s_phi[0][w2] + s_phi[1][w2] + s_phi[2][w2] + s_phi[3][w2];
        else         sum = s_plo[0][w2] + s_plo[1][w2] + s_plo[2][w2] + s_plo[3][w2];
        if (sum) atomicAdd(&g_hist[b * NC + tid], sum);   // cnt_x + cnt_t
        const int in = s_inter[tid];
        if (in)  atomicAdd(&g_inter[b * NC + tid], in);
    }
}

__global__ __launch_bounds__(64) void finalize_kernel(const int* __restrict__ g_hist,
                                                      const int* __restrict__ g_inter,
                                                      const float* __restrict__ smooth,
                                                      float* __restrict__ out) {
    const int b = blockIdx.x;
    const int lane = threadIdx.x;  // 0..63
    const float s = smooth[0];
    float acc = 0.0f;
    for (int c = lane; c < NC; c += 64) {
        float in = (float)g_inter[b * NC + c];
        float ht = (float)g_hist[b * NC + c];   // cnt_x + cnt_t
        // union = cnt_x + cnt_t - inter
        acc += (in + s) / (ht - in + s);
    }
#pragma unroll
    for (int off = 32; off > 0; off >>= 1)
        acc += __shfl_down(acc, off, 64);
    if (lane == 0) out[b] = acc / (float)NC;
}

extern "C" void kernel_launch(void* const* d_in, const int* in_sizes, int n_in,
                              void* d_out, int out_size, void* d_ws, size_t ws_size,
                              hipStream_t stream) {
    const int* x = (const int*)d_in[0];
    const int* t = (const int*)d_in[1];
    const float* smooth = (const float*)d_in[2];
    float* out = (float*)d_out;

    int* g_hist = (int*)d_ws;
    int* g_inter = g_hist + NB * NC;

    hipMemsetAsync(d_ws, 0, 2 * NB * NC * sizeof(int), stream);

    dim3 grid(HW / PIX_PER_BLOCK, NB);  // 32 x 32 = 1024 blocks (4 per CU)
    hist_kernel<<<grid, THREADS, 0, stream>>>(x, t, g_hist, g_inter);
    finalize_kernel<<<NB, 64, 0, stream>>>(g_hist, g_inter, smooth, out);
}

// Round 2
// 285.585 us; speedup vs baseline: 1.0437x; 1.0437x over previous
//
#include <hip/hip_runtime.h>

#define NC 91
#define NB 32
#define HW (1024 * 1024)

#define THREADS 256
#define PPT 64                          // pixels per thread
#define PIX_PER_BLOCK (THREADS * PPT)   // 16384
#define WPT 23                          // ceil(91/4) words, odd stride -> full bank spread

// Per-thread private histogram, 4 bins packed per 32-bit word (8-bit fields).
// Max increments per thread per bin = 2*PPT = 128 <= 255, so no field carry.
// atomicAdd on a private address compiles to fire-and-forget ds_add_u32:
// 1 DS instruction per increment, zero same-address contention.
// LDS/block ~26 KB -> 6 blocks/CU (24 waves, 75% occupancy) vs 2 blocks before.

__global__ __launch_bounds__(256) void hist_kernel(const int* __restrict__ x,
                                                   const int* __restrict__ t,
                                                   int* __restrict__ g_hist,
                                                   int* __restrict__ g_inter) {
    __shared__ int s_hist[THREADS * WPT];   // 23,552 B packed private histograms
    __shared__ int s_inter[NC];             // block-wide intersection (rare hits)
    __shared__ int s_p[8][WPT * 4];         // stage-1 partials (8 chunks x 92 classes)

    const int tid = threadIdx.x;
    int* hp = &s_hist[tid * WPT];
#pragma unroll
    for (int j = 0; j < WPT; ++j) hp[j] = 0;
    if (tid < NC) s_inter[tid] = 0;
    __syncthreads();

    const int b = blockIdx.y;
    const long base = (long)b * HW + (long)blockIdx.x * PIX_PER_BLOCK;
    const int4* __restrict__ x4 = (const int4*)(x + base);
    const int4* __restrict__ t4 = (const int4*)(t + base);

#pragma unroll 4
    for (int i = 0; i < PPT / 4; ++i) {
        int4 xv = x4[i * THREADS + tid];
        int4 tv = t4[i * THREADS + tid];

        atomicAdd(&hp[xv.x >> 2], 1 << ((xv.x & 3) << 3));
        atomicAdd(&hp[tv.x >> 2], 1 << ((tv.x & 3) << 3));
        if (xv.x == tv.x) atomicAdd(&s_inter[xv.x], 1);

        atomicAdd(&hp[xv.y >> 2], 1 << ((xv.y & 3) << 3));
        atomicAdd(&hp[tv.y >> 2], 1 << ((tv.y & 3) << 3));
        if (xv.y == tv.y) atomicAdd(&s_inter[xv.y], 1);

        atomicAdd(&hp[xv.z >> 2], 1 << ((xv.z & 3) << 3));
        atomicAdd(&hp[tv.z >> 2], 1 << ((tv.z & 3) << 3));
        if (xv.z == tv.z) atomicAdd(&s_inter[xv.z], 1);

        atomicAdd(&hp[xv.w >> 2], 1 << ((xv.w & 3) << 3));
        atomicAdd(&hp[tv.w >> 2], 1 << ((tv.w & 3) << 3));
        if (xv.w == tv.w) atomicAdd(&s_inter[xv.w], 1);
    }
    __syncthreads();

    // Stage 1: reduce 256 private copies in 8 chunks of 32, unpacking 8-bit
    // fields into 32-bit partials (max 32*255 = 8160 per field, no overflow).
    // Per wave: 2 chunks x 32 lanes -> addresses differ by 32*WPT words
    // (736 % 32 == 0) -> exactly 2-way bank aliasing, which is free.
    const int chunk = tid >> 5;
    const int w = tid & 31;
    if (w < WPT) {
        int f0 = 0, f1 = 0, f2 = 0, f3 = 0;
        const int kb = chunk * 32;
        for (int k = 0; k < 32; ++k) {
            unsigned v = (unsigned)s_hist[(kb + k) * WPT + w];
            f0 += (int)(v & 0xffu);
            f1 += (int)((v >> 8) & 0xffu);
            f2 += (int)((v >> 16) & 0xffu);
            f3 += (int)(v >> 24);
        }
        s_p[chunk][w * 4 + 0] = f0;
        s_p[chunk][w * 4 + 1] = f1;
        s_p[chunk][w * 4 + 2] = f2;
        s_p[chunk][w * 4 + 3] = f3;
    }
    __syncthreads();

    // Stage 2: combine 8 chunk partials, one global atomic per class.
    if (tid < NC) {
        int sum = 0;
#pragma unroll
        for (int ch = 0; ch < 8; ++ch) sum += s_p[ch][tid];
        if (sum) atomicAdd(&g_hist[b * NC + tid], sum);   // cnt_x + cnt_t
        const int in = s_inter[tid];
        if (in)  atomicAdd(&g_inter[b * NC + tid], in);
    }
}

__global__ __launch_bounds__(64) void finalize_kernel(const int* __restrict__ g_hist,
                                                      const int* __restrict__ g_inter,
                                                      const float* __restrict__ smooth,
                                                      float* __restrict__ out) {
    const int b = blockIdx.x;
    const int lane = threadIdx.x;  // 0..63
    const float s = smooth[0];
    float acc = 0.0f;
    for (int c = lane; c < NC; c += 64) {
        float in = (float)g_inter[b * NC + c];
        float ht = (float)g_hist[b * NC + c];   // cnt_x + cnt_t
        // union = cnt_x + cnt_t - inter
        acc += (in + s) / (ht - in + s);
    }
#pragma unroll
    for (int off = 32; off > 0; off >>= 1)
        acc += __shfl_down(acc, off, 64);
    if (lane == 0) out[b] = acc / (float)NC;
}

extern "C" void kernel_launch(void* const* d_in, const int* in_sizes, int n_in,
                              void* d_out, int out_size, void* d_ws, size_t ws_size,
                              hipStream_t stream) {
    const int* x = (const int*)d_in[0];
    const int* t = (const int*)d_in[1];
    const float* smooth = (const float*)d_in[2];
    float* out = (float*)d_out;

    int* g_hist = (int*)d_ws;
    int* g_inter = g_hist + NB * NC;

    hipMemsetAsync(d_ws, 0, 2 * NB * NC * sizeof(int), stream);

    dim3 grid(HW / PIX_PER_BLOCK, NB);  // 64 x 32 = 2048 blocks (8 per CU)
    hist_kernel<<<grid, THREADS, 0, stream>>>(x, t, g_hist, g_inter);
    finalize_kernel<<<NB, 64, 0, stream>>>(g_hist, g_inter, smooth, out);
}